// Round 5
// baseline (382.010 us; speedup 1.0000x reference)
//
#include <hip/hip_runtime.h>
#include <hip/hip_bf16.h>

// GaussianConv: 5-layer KNN conv net on point cloud.
// R5: conv0 reg-staged A (issue-early/write-late, swizzled ds_write, dbuf)
// -> no vmcnt(0) barrier drain; knn idx hoisted to regs; all intermediate
// activations f16 (halved gather traffic, no staging conversion);
// composed layer-3 indices precomputed. Whole net f16 MFMA.

typedef __attribute__((ext_vector_type(8))) _Float16 f16x8;
typedef __attribute__((ext_vector_type(4))) float f32x4;
typedef __attribute__((ext_vector_type(8))) unsigned short u16x8;

#define NPTS 100000
#define N1PTS 12500

// Swizzled LDS offset for [64 rows][64 k] f16 tiles.
__device__ __forceinline__ int swz(int r, int k) {
  return r * 64 + ((((k >> 3) ^ r) & 7) << 3) + (k & 7);
}

__device__ __forceinline__ unsigned short f16bits(float x) {
  return __builtin_bit_cast(unsigned short, (_Float16)x);
}

// layers 1-4 weights: f32 -> f16 row-major
__global__ void prepack_w(const float* __restrict__ W, unsigned short* __restrict__ out,
                          int n) {
  int i = blockIdx.x * 256 + threadIdx.x;
  if (i < n) out[i] = f16bits(W[i]);
}

// Layer-0 weights -> MFMA-fragment-native packed f16:
// group g = (((c*4 + w)*4 + n)*2 + s), lane l, elem e:
//   dest[g*512 + l*8 + e] = W[w*64+n*16+(l&15)][c*64 + s*32 + (l>>4)*8 + e]
__global__ void prepack_w0(const float* __restrict__ W, unsigned short* __restrict__ out) {
  const int tid = blockIdx.x * 256 + threadIdx.x;  // 65536 total
  const int l = tid & 63;
  const int s = (tid >> 6) & 1;
  const int n = (tid >> 7) & 3;
  const int w = (tid >> 9) & 3;
  const int c = tid >> 11;  // 0..31
  const int co = w * 64 + n * 16 + (l & 15);
  const int k = c * 64 + s * 32 + ((l >> 4) << 3);
  const float* src = W + (size_t)co * 2048 + k;
  u16x8 h;
#pragma unroll
  for (int e = 0; e < 8; ++e) h[e] = f16bits(src[e]);
  ((u16x8*)out)[tid] = h;
}

// features f32 -> f16, 8 elems/thread
__global__ void prepack_feat(const float* __restrict__ F, unsigned short* __restrict__ out,
                             int n8) {
  int i = blockIdx.x * 256 + threadIdx.x;
  if (i >= n8) return;
  const float4* s = (const float4*)(F + (size_t)i * 8);
  float4 v0 = s[0], v1 = s[1];
  float x[8] = {v0.x, v0.y, v0.z, v0.w, v1.x, v1.y, v1.z, v1.w};
  u16x8 o;
#pragma unroll
  for (int e = 0; e < 8; ++e) o[e] = f16bits(x[e]);
  ((u16x8*)out)[i] = o;
}

__global__ void count_labels(const int* __restrict__ labels, int* __restrict__ cnt) {
  int i = blockIdx.x * 256 + threadIdx.x;
  if (i < NPTS) atomicAdd(&cnt[labels[i]], 1);
}

// composed layer-3 gather indices: labels[knn0[.]]
__global__ void compose_idx(const int* __restrict__ knn0, const int* __restrict__ labels,
                            int* __restrict__ out) {
  int i = blockIdx.x * 256 + threadIdx.x;
  if (i < NPTS * 8) out[i] = labels[knn0[i]];
}

__global__ void finalize_pool(const int* __restrict__ pool, const int* __restrict__ cnt,
                              unsigned short* __restrict__ out) {
  int i = blockIdx.x * 256 + threadIdx.x;
  if (i >= N1PTS * 256) return;
  float denom = fmaxf((float)cnt[i >> 8], 1.0f);
  out[i] = f16bits(((float)pool[i]) * (1.0f / 16777216.0f) / denom);
}

// ---------------- Layer 0 ----------------
// 1563 blocks x 256 thr (4 waves). Tile 64 rows x 256 cols; wave w owns cols
// [w*64,+64) -> acc[4][4]. A: reg-staged gather (global->VGPR issued one
// chunk early, swizzled ds_write_b128 late), double-buffered LDS. B: coalesced
// fragment-packed weights (L2-resident 1MB) straight to MFMA regs.
__global__ __launch_bounds__(256) void conv0_gemm(
    const unsigned short* __restrict__ F16, const int* __restrict__ idx,
    const int* __restrict__ lab, const unsigned short* __restrict__ Wpk,
    const float* __restrict__ bias, int* __restrict__ pool) {
  __shared__ alignas(16) unsigned short sA[2][64 * 64];  // 8KB x2

  const int t = threadIdx.x;
  const int w = t >> 6, l = t & 63;
  const int lr = l & 15, lh = l >> 4;
  const int row0 = blockIdx.x * 64;

  // staging: thread t stages row sr = t>>2, 32B chunk (t&3) -> segs seg0, seg0+1
  const int sr = t >> 2;
  const int grow = row0 + sr;
  const int seg0 = (t & 3) * 2;
  const int wo0 = sr * 64 + (((seg0) ^ (sr & 7)) << 3);
  const int wo1 = sr * 64 + (((seg0 + 1) ^ (sr & 7)) << 3);

  // hoist all 8 neighbor ids for this row (shared by 4 threads; L1 broadcast)
  int nbs[8];
  {
    const int rr = (grow < NPTS) ? grow : 0;
    const int4* ip = (const int4*)(idx + rr * 8);
    int4 i0 = ip[0], i1 = ip[1];
    nbs[0] = i0.x; nbs[1] = i0.y; nbs[2] = i0.z; nbs[3] = i0.w;
    nbs[4] = i1.x; nbs[5] = i1.y; nbs[6] = i1.z; nbs[7] = i1.w;
  }

  f32x4 acc[4][4] = {};

  auto asrc = [&](int c) -> const u16x8* {
    return (const u16x8*)(F16 + ((size_t)nbs[c >> 2] << 8) + ((c & 3) << 6) + seg0 * 8);
  };

  // prologue: stage chunk 0
  {
    const u16x8* s = asrc(0);
    u16x8 a0 = s[0], a1 = s[1];
    *(u16x8*)&sA[0][wo0] = a0;
    *(u16x8*)&sA[0][wo1] = a1;
  }
  __syncthreads();

  for (int c = 0; c < 32; ++c) {
    const int b = c & 1;

    // issue next chunk's gather loads FIRST (hidden under B-wait + MFMAs)
    u16x8 a0, a1;
    if (c < 31) {
      const u16x8* s = asrc(c + 1);
      a0 = s[0]; a1 = s[1];
    }

    // B fragments: coalesced 1KB/wave-instr from packed weights
    f16x8 bh[2][4];
#pragma unroll
    for (int s = 0; s < 2; ++s)
#pragma unroll
      for (int n = 0; n < 4; ++n) {
        const size_t base = ((((size_t)c * 4 + w) * 4 + n) * 2 + s) * 512 + (size_t)l * 8;
        bh[s][n] = *(const f16x8*)(Wpk + base);
      }

#pragma unroll
    for (int s = 0; s < 2; ++s) {
      f16x8 a[4];
#pragma unroll
      for (int m = 0; m < 4; ++m) {
        const int seg = ((s << 2) + lh) ^ (lr & 7);
        a[m] = *(const f16x8*)&sA[b][(m * 16 + lr) * 64 + (seg << 3)];
      }
#pragma unroll
      for (int n = 0; n < 4; ++n)
#pragma unroll
        for (int m = 0; m < 4; ++m)
          acc[m][n] = __builtin_amdgcn_mfma_f32_16x16x32_f16(a[m], bh[s][n], acc[m][n], 0, 0, 0);
    }

    // write-late: stage next chunk into the other buffer (waits only a0/a1)
    if (c < 31) {
      *(u16x8*)&sA[b ^ 1][wo0] = a0;
      *(u16x8*)&sA[b ^ 1][wo1] = a1;
    }
    __syncthreads();  // drains LDS ops only; no vmem outstanding
  }

  // epilogue: C frag col = lane&15, row = (lane>>4)*4 + r
  float bv[4];
#pragma unroll
  for (int n = 0; n < 4; ++n) bv[n] = bias[w * 64 + n * 16 + lr];
#pragma unroll
  for (int m = 0; m < 4; ++m) {
#pragma unroll
    for (int r = 0; r < 4; ++r) {
      const int i = row0 + m * 16 + lh * 4 + r;
      if (i < NPTS) {
        const int lb = lab[i];
#pragma unroll
        for (int n = 0; n < 4; ++n) {
          float z = acc[m][n][r] + bv[n];
          z = 1.0f / (1.0f + expf(-z));
          atomicAdd(&pool[(size_t)lb * 256 + (w * 64 + n * 16 + lr)],
                    __float2int_rn(z * 16777216.0f));
        }
      }
    }
  }
}

// ---------------- Layers 1-4: LDS-staged f16 GEMM, f16 activations ----------
template <bool ACT, bool OUT16>
__global__ __launch_bounds__(256, 2) void conv_gemm(
    const unsigned short* __restrict__ act16, const int* __restrict__ idx,
    const unsigned short* __restrict__ Wf, const float* __restrict__ bias,
    void* __restrict__ outp, int M, int cinShift, int Cout, int Ktot) {
  __shared__ alignas(16) unsigned short sAh[4096];
  __shared__ alignas(16) unsigned short sBh[4096];

  const int Cin = 1 << cinShift;
  const int t = threadIdx.x;
  const int bm = blockIdx.x, bn = blockIdx.y;

  const int sr = t >> 2;
  const int kseg = (t & 3) << 4;
  const int ai = bm * 64 + sr;
  const int bco = bn * 64 + sr;

  f32x4 acc[4] = {};

  const int nch = Ktot >> 6;
  for (int kc = 0; kc < nch; ++kc) {
    const int kg = (kc << 6) + kseg;

    u16x8 h0 = {}, h1 = {};
    if (ai < M) {
      const int j = kg >> cinShift;
      const int nbv = idx[ai * 8 + j];
      const unsigned short* src = act16 + ((size_t)nbv << cinShift) + (kg & (Cin - 1));
      h0 = ((const u16x8*)src)[0];
      h1 = ((const u16x8*)src)[1];
    }

    u16x8 bh0 = {}, bh1 = {};
    if (bco < Cout) {
      const unsigned short* sw = Wf + (size_t)bco * Ktot + kg;
      bh0 = ((const u16x8*)sw)[0];
      bh1 = ((const u16x8*)sw)[1];
    }

    __syncthreads();
    const int w0 = swz(sr, kseg), w1 = swz(sr, kseg + 8);
    *(u16x8*)&sAh[w0] = h0; *(u16x8*)&sAh[w1] = h1;
    *(u16x8*)&sBh[w0] = bh0; *(u16x8*)&sBh[w1] = bh1;
    __syncthreads();

    const int l = t & 63;
    const int lr = l & 15, lh = l >> 4;
    const int wid = t >> 6;
#pragma unroll
    for (int s = 0; s < 2; ++s) {
      const int kb = s * 32 + lh * 8;
      const int boff = swz(wid * 16 + lr, kb);
      f16x8 bh = *(const f16x8*)&sBh[boff];
#pragma unroll
      for (int m = 0; m < 4; ++m) {
        const int aoff = swz(m * 16 + lr, kb);
        f16x8 ah = *(const f16x8*)&sAh[aoff];
        acc[m] = __builtin_amdgcn_mfma_f32_16x16x32_f16(ah, bh, acc[m], 0, 0, 0);
      }
    }
  }

  const int l = t & 63, wid = t >> 6;
  const int lr = l & 15, lh = l >> 4;
  const int co = bn * 64 + wid * 16 + lr;
  if (co < Cout) {
    const float bvv = bias[co];
#pragma unroll
    for (int m = 0; m < 4; ++m) {
#pragma unroll
      for (int r = 0; r < 4; ++r) {
        const int i = bm * 64 + m * 16 + lh * 4 + r;
        if (i < M) {
          float z = acc[m][r] + bvv;
          if (ACT) z = 1.0f / (1.0f + expf(-z));
          if (OUT16)
            ((unsigned short*)outp)[(size_t)i * Cout + co] = f16bits(z);
          else
            ((float*)outp)[(size_t)i * Cout + co] = z;
        }
      }
    }
  }
}

extern "C" void kernel_launch(void* const* d_in, const int* in_sizes, int n_in,
                              void* d_out, int out_size, void* d_ws, size_t ws_size,
                              hipStream_t stream) {
  const float* features = (const float*)d_in[0];
  const int* knn0 = (const int*)d_in[1];
  const int* knn1 = (const int*)d_in[2];
  const int* labels = (const int*)d_in[3];
  const float* kw[5] = {(const float*)d_in[4], (const float*)d_in[6],
                        (const float*)d_in[8], (const float*)d_in[10],
                        (const float*)d_in[12]};
  const float* bw[5] = {(const float*)d_in[5], (const float*)d_in[7],
                        (const float*)d_in[9], (const float*)d_in[11],
                        (const float*)d_in[13]};

  char* ws = (char*)d_ws;
  size_t off = 0;
  auto alloc = [&](size_t bytes) -> void* {
    void* p = ws + off;
    off = (off + bytes + 255) & ~(size_t)255;
    return p;
  };
  unsigned short* Wpk0 = (unsigned short*)alloc((size_t)524288 * 2);
  const int wsz14[4] = {262144, 65536, 16384, 768};
  const int woff14[4] = {0, 262144, 327680, 344064};
  unsigned short* W14 = (unsigned short*)alloc((size_t)344832 * 2);
  int* pool = (int*)alloc((size_t)N1PTS * 256 * 4);
  int* cnt = (int*)alloc((size_t)N1PTS * 4);
  unsigned short* pooled = (unsigned short*)alloc((size_t)N1PTS * 256 * 2);
  unsigned short* f1 = (unsigned short*)alloc((size_t)N1PTS * 128 * 2);
  unsigned short* f2 = (unsigned short*)alloc((size_t)N1PTS * 64 * 2);
  int* idx3 = (int*)alloc((size_t)NPTS * 8 * 4);
  unsigned short* F16 = (unsigned short*)alloc((size_t)NPTS * 256 * 2);
  unsigned short* f3 = (unsigned short*)pool;  // alias: pool consumed before layer 3
  if (off > ws_size) return;

  // 1. prepack weights + features (f16); composed layer-3 indices
  prepack_w0<<<256, 256, 0, stream>>>(kw[0], Wpk0);
  for (int i = 0; i < 4; ++i)
    prepack_w<<<(wsz14[i] + 255) / 256, 256, 0, stream>>>(kw[i + 1], W14 + woff14[i], wsz14[i]);
  prepack_feat<<<(NPTS * 256 / 8 + 255) / 256, 256, 0, stream>>>(features, F16, NPTS * 256 / 8);
  compose_idx<<<(NPTS * 8 + 255) / 256, 256, 0, stream>>>(knn0, labels, idx3);

  // 2. zero pool+cnt, histogram labels
  hipMemsetAsync(pool, 0, (size_t)N1PTS * 256 * 4 + (size_t)N1PTS * 4, stream);
  count_labels<<<(NPTS + 255) / 256, 256, 0, stream>>>(labels, cnt);

  // 3. layer 0 + fused fixed-point pool scatter
  conv0_gemm<<<1563, 256, 0, stream>>>(F16, knn0, labels, Wpk0, bw[0], pool);

  // 4. pooled mean -> f16 [N1,256]
  finalize_pool<<<(N1PTS * 256 + 255) / 256, 256, 0, stream>>>(pool, cnt, pooled);

  dim3 blk(256);
  // 5. layer 1: pooled -> f1 [N1,128] f16
  conv_gemm<true, true><<<dim3(196, 2), blk, 0, stream>>>(
      pooled, knn1, W14 + woff14[0], bw[1], f1, N1PTS, 8, 128, 2048);
  // 6. layer 2: f1 -> f2 [N1,64] f16
  conv_gemm<true, true><<<dim3(196, 1), blk, 0, stream>>>(
      f1, knn1, W14 + woff14[1], bw[2], f2, N1PTS, 7, 64, 1024);
  // 7. layer 3: gather f2[idx3] -> f3 [N,32] f16
  conv_gemm<true, true><<<dim3(1563, 1), blk, 0, stream>>>(
      f2, idx3, W14 + woff14[2], bw[3], f3, NPTS, 6, 32, 512);
  // 8. layer 4: f3 -> out [N,3] f32, no activation
  conv_gemm<false, false><<<dim3(1563, 1), blk, 0, stream>>>(
      f3, knn0, W14 + woff14[3], bw[4], (float*)d_out, NPTS, 5, 3, 256);
}